// Round 2
// baseline (225.193 us; speedup 1.0000x reference)
//
#include <hip/hip_runtime.h>

#define BTOT 1048576
#define D 17
#define H 8
#define OUT 6
#define E 4
#define G1 64
#define G2 32

typedef float v2f __attribute__((ext_vector_type(2)));

// v_pk_fma_f32: per-lane 2x fp32 FMA. Weight pair comes from SGPRs (uniform
// address -> s_load), x/h operand is one scalar of a packed VGPR pair,
// broadcast to both halves via op_sel / op_sel_hi (no v_mov broadcast needed).
// LO: both halves use xp.low ; HI: both halves use xp.high.
#define PKFMA_LO(acc, xp, wp)                                              \
    asm("v_pk_fma_f32 %0, %1, %2, %0 op_sel:[0,0,0] op_sel_hi:[0,1,1]"     \
        : "+v"(acc) : "v"(xp), "s"(wp))
#define PKFMA_HI(acc, xp, wp)                                              \
    asm("v_pk_fma_f32 %0, %1, %2, %0 op_sel:[1,0,0] op_sel_hi:[1,1,1]"     \
        : "+v"(acc) : "v"(xp), "s"(wp))

__global__ __launch_bounds__(256) void hybrid_ruc_kernel(
    const float* __restrict__ x,
    const float* __restrict__ eW1, const float* __restrict__ eb1,
    const float* __restrict__ eW2, const float* __restrict__ eb2,
    const float* __restrict__ eW3, const float* __restrict__ eb3,
    const float* __restrict__ gW1, const float* __restrict__ gb1,
    const float* __restrict__ gW2, const float* __restrict__ gb2,
    const float* __restrict__ gW3, const float* __restrict__ gb3,
    float* __restrict__ out)
{
    const long long b = (long long)blockIdx.x * 256 + threadIdx.x;

    // ---- x row: direct scalar loads (wave covers a contiguous 4.4KB window
    // per step -> L1/L2 resident; VMEM has huge slack). Pack into v2f pairs
    // so PKFMA_LO/HI can select halves without broadcast movs. ----
    float xr[D];
    #pragma unroll
    for (int i = 0; i < D; ++i) xr[i] = x[b * D + i];
    v2f xp[9];
    #pragma unroll
    for (int k = 0; k < 8; ++k) { xp[k].x = xr[2 * k]; xp[k].y = xr[2 * k + 1]; }
    xp[8].x = xr[16]; xp[8].y = 0.0f;

    // ---- gating layer1 (17->64) fused with layer2 (64->32), 16-wide tiles ----
    v2f h2p[G2 / 2];
    #pragma unroll
    for (int j = 0; j < G2 / 2; ++j) h2p[j] = *(const v2f*)(gb2 + 2 * j);

    #pragma unroll 1
    for (int jt = 0; jt < G1 / 16; ++jt) {
        v2f a[8];
        #pragma unroll
        for (int c = 0; c < 8; ++c) a[c] = *(const v2f*)(gb1 + jt * 16 + 2 * c);
        #pragma unroll
        for (int k = 0; k < 8; ++k) {          // i = 2k, 2k+1 (ascending order kept)
            const float* r0 = gW1 + (2 * k) * G1 + jt * 16;
            const float* r1 = gW1 + (2 * k + 1) * G1 + jt * 16;
            #pragma unroll
            for (int c = 0; c < 8; ++c) {
                v2f w = *(const v2f*)(r0 + 2 * c);
                PKFMA_LO(a[c], xp[k], w);
            }
            #pragma unroll
            for (int c = 0; c < 8; ++c) {
                v2f w = *(const v2f*)(r1 + 2 * c);
                PKFMA_HI(a[c], xp[k], w);
            }
        }
        {   // tail i = 16
            const float* r = gW1 + 16 * G1 + jt * 16;
            #pragma unroll
            for (int c = 0; c < 8; ++c) {
                v2f w = *(const v2f*)(r + 2 * c);
                PKFMA_LO(a[c], xp[8], w);
            }
        }
        // relu on components, then layer2: h1[c] broadcast into 16 h2 pairs
        #pragma unroll
        for (int c = 0; c < 8; ++c) {
            a[c].x = fmaxf(a[c].x, 0.0f);
            a[c].y = fmaxf(a[c].y, 0.0f);
        }
        #pragma unroll
        for (int c = 0; c < 8; ++c) {          // h1 index = jt*16 + 2c, 2c+1
            const float* r0 = gW2 + (jt * 16 + 2 * c) * G2;
            const float* r1 = gW2 + (jt * 16 + 2 * c + 1) * G2;
            #pragma unroll
            for (int j = 0; j < 16; ++j) {
                v2f w = *(const v2f*)(r0 + 2 * j);
                PKFMA_LO(h2p[j], a[c], w);
            }
            #pragma unroll
            for (int j = 0; j < 16; ++j) {
                v2f w = *(const v2f*)(r1 + 2 * j);
                PKFMA_HI(h2p[j], a[c], w);
            }
        }
    }

    // ---- gating layer3 (32->4): raw logits (relu applied to h2 only) ----
    v2f lgp[2];
    lgp[0] = *(const v2f*)(gb3);
    lgp[1] = *(const v2f*)(gb3 + 2);
    #pragma unroll
    for (int j2 = 0; j2 < 16; ++j2) {          // j = 2*j2, 2*j2+1 ascending
        h2p[j2].x = fmaxf(h2p[j2].x, 0.0f);
        h2p[j2].y = fmaxf(h2p[j2].y, 0.0f);
        const float* r0 = gW3 + (2 * j2) * E;
        const float* r1 = gW3 + (2 * j2 + 1) * E;
        v2f w00 = *(const v2f*)(r0);
        v2f w01 = *(const v2f*)(r0 + 2);
        PKFMA_LO(lgp[0], h2p[j2], w00);
        PKFMA_LO(lgp[1], h2p[j2], w01);
        v2f w10 = *(const v2f*)(r1);
        v2f w11 = *(const v2f*)(r1 + 2);
        PKFMA_HI(lgp[0], h2p[j2], w10);
        PKFMA_HI(lgp[1], h2p[j2], w11);
    }

    // ---- argmax, first-max-wins (matches jnp.argmax) ----
    float lg[E] = { lgp[0].x, lgp[0].y, lgp[1].x, lgp[1].y };
    int sel = 0;
    float best = lg[0];
    #pragma unroll
    for (int e = 1; e < E; ++e) {
        if (lg[e] > best) { best = lg[e]; sel = e; }
    }

    // ---- experts: all 4 with uniform SGPR weights, branch-free select ----
    v2f predp[3];
    #pragma unroll
    for (int p = 0; p < 3; ++p) { predp[p].x = 0.0f; predp[p].y = 0.0f; }

    #pragma unroll 1
    for (int e = 0; e < E; ++e) {
        // layer1: 17 -> 8
        v2f t1p[4];
        #pragma unroll
        for (int h = 0; h < 4; ++h) t1p[h] = *(const v2f*)(eb1 + e * H + 2 * h);
        #pragma unroll
        for (int k = 0; k < 8; ++k) {
            const float* r0 = eW1 + e * D * H + (2 * k) * H;
            const float* r1 = eW1 + e * D * H + (2 * k + 1) * H;
            #pragma unroll
            for (int h = 0; h < 4; ++h) {
                v2f w = *(const v2f*)(r0 + 2 * h);
                PKFMA_LO(t1p[h], xp[k], w);
            }
            #pragma unroll
            for (int h = 0; h < 4; ++h) {
                v2f w = *(const v2f*)(r1 + 2 * h);
                PKFMA_HI(t1p[h], xp[k], w);
            }
        }
        {   // tail i = 16
            const float* r = eW1 + e * D * H + 16 * H;
            #pragma unroll
            for (int h = 0; h < 4; ++h) {
                v2f w = *(const v2f*)(r + 2 * h);
                PKFMA_LO(t1p[h], xp[8], w);
            }
        }
        #pragma unroll
        for (int h = 0; h < 4; ++h) {
            t1p[h].x = fmaxf(t1p[h].x, 0.0f);
            t1p[h].y = fmaxf(t1p[h].y, 0.0f);
        }
        // layer2: 8 -> 8
        v2f t2p[4];
        #pragma unroll
        for (int h = 0; h < 4; ++h) t2p[h] = *(const v2f*)(eb2 + e * H + 2 * h);
        #pragma unroll
        for (int k2 = 0; k2 < 4; ++k2) {       // k = 2*k2, 2*k2+1
            const float* r0 = eW2 + e * H * H + (2 * k2) * H;
            const float* r1 = eW2 + e * H * H + (2 * k2 + 1) * H;
            #pragma unroll
            for (int h = 0; h < 4; ++h) {
                v2f w = *(const v2f*)(r0 + 2 * h);
                PKFMA_LO(t2p[h], t1p[k2], w);
            }
            #pragma unroll
            for (int h = 0; h < 4; ++h) {
                v2f w = *(const v2f*)(r1 + 2 * h);
                PKFMA_HI(t2p[h], t1p[k2], w);
            }
        }
        #pragma unroll
        for (int h = 0; h < 4; ++h) {
            t2p[h].x = fmaxf(t2p[h].x, 0.0f);
            t2p[h].y = fmaxf(t2p[h].y, 0.0f);
        }
        // layer3: 8 -> 6
        v2f pop[3];
        #pragma unroll
        for (int p = 0; p < 3; ++p) pop[p] = *(const v2f*)(eb3 + e * OUT + 2 * p);
        #pragma unroll
        for (int k2 = 0; k2 < 4; ++k2) {       // k = 2*k2, 2*k2+1
            const float* r0 = eW3 + e * H * OUT + (2 * k2) * OUT;
            const float* r1 = eW3 + e * H * OUT + (2 * k2 + 1) * OUT;
            #pragma unroll
            for (int p = 0; p < 3; ++p) {
                v2f w = *(const v2f*)(r0 + 2 * p);
                PKFMA_LO(pop[p], t2p[k2], w);
            }
            #pragma unroll
            for (int p = 0; p < 3; ++p) {
                v2f w = *(const v2f*)(r1 + 2 * p);
                PKFMA_HI(pop[p], t2p[k2], w);
            }
        }
        const bool m = (sel == e);             // exactly one e matches
        #pragma unroll
        for (int p = 0; p < 3; ++p) predp[p] = m ? pop[p] : predp[p];
    }

    // ---- stores: predictions [B,6] then logits [B,4], vectorized ----
    float* po = out + b * OUT;                  // b*24 bytes: 8B aligned
    *(v2f*)(po)     = predp[0];
    *(v2f*)(po + 2) = predp[1];
    *(v2f*)(po + 4) = predp[2];
    float* lo = out + (long long)BTOT * OUT + b * E;  // b*16 bytes aligned
    *(v2f*)(lo)     = lgp[0];
    *(v2f*)(lo + 2) = lgp[1];
}

extern "C" void kernel_launch(void* const* d_in, const int* in_sizes, int n_in,
                              void* d_out, int out_size, void* d_ws, size_t ws_size,
                              hipStream_t stream) {
    const float* x   = (const float*)d_in[0];
    const float* eW1 = (const float*)d_in[1];
    const float* eb1 = (const float*)d_in[2];
    const float* eW2 = (const float*)d_in[3];
    const float* eb2 = (const float*)d_in[4];
    const float* eW3 = (const float*)d_in[5];
    const float* eb3 = (const float*)d_in[6];
    const float* gW1 = (const float*)d_in[7];
    const float* gb1 = (const float*)d_in[8];
    const float* gW2 = (const float*)d_in[9];
    const float* gb2 = (const float*)d_in[10];
    const float* gW3 = (const float*)d_in[11];
    const float* gb3 = (const float*)d_in[12];
    float* out = (float*)d_out;

    dim3 grid(BTOT / 256), block(256);
    hipLaunchKernelGGL(hybrid_ruc_kernel, grid, block, 0, stream,
                       x, eW1, eb1, eW2, eb2, eW3, eb3,
                       gW1, gb1, gW2, gb2, gW3, gb3, out);
}